// Round 13
// baseline (348.756 us; speedup 1.0000x reference)
//
#include <hip/hip_runtime.h>
#include <hip/hip_cooperative_groups.h>
#include <math.h>

namespace cg = cooperative_groups;

// RBF mixture: out[i] = sum_m w_m * exp(-(x_i-mu_m)^T C_m (x_i-mu_m)), C_m = G_m G_m^T
// N=32768, M=2048, D=32.
// Round 13: single cooperative kernel (256 blocks x 512 thr, 147 KB dyn LDS,
// 1 block/CU co-resident). Phases: zero | build-B (8 m/blk) | grid.sync |
// r12 screen body | grid.sync | per-m survivor buckets + fallback | grid.sync
// | finalize. Eliminates ~5 dispatch overheads (~40 us of the r12 total's
// 83 us non-screen time). Screen body unchanged from r12 (102 us, 31% Mfma).

#define NN 32768
#define MM 2048
#define DDIM 32
#define KSYM 576           // 528 triangle + 32 cross + 2 const + 14 pad = 18*32
#define ROWS 128           // i-rows per screen block
#define KSTEPS 18
#define SCREEN 120.0f
#define MCAP 2048
#define FCAP 1000000
#define GRID 256
#define TPB 512

typedef __attribute__((ext_vector_type(8))) short short8;
typedef __attribute__((ext_vector_type(4))) float floatx4;

__device__ __forceinline__ unsigned int to_bf16(float f) {
  union { float f; unsigned int u; } x; x.f = f;
  return (x.u + 0x7fffu + ((x.u >> 16) & 1u)) >> 16;   // RNE, finite inputs only
}

struct DFTab { unsigned char d[528]; unsigned char f[528]; };
constexpr DFTab make_df() {
  DFTab t{};
  int s = 0;
  for (int d = 0; d < 32; ++d)
    for (int f = d; f < 32; ++f) {
      t.d[s] = (unsigned char)d; t.f[s] = (unsigned char)f; ++s;
    }
  return t;
}
constexpr DFTab DFT = make_df();

__device__ __forceinline__ float slot_val(const float* v, int s) {
  if (s < 528) return v[DFT.d[s]] * v[DFT.f[s]];
  if (s < 560) return v[s - 528];
  if (s < 562) return 1.f;
  return 0.f;
}

__device__ __forceinline__ void slot_df(int s, int* dd, int* ff) {
  int d = 0, b = 0;
  while (b + (DDIM - d) <= s) { b += DDIM - d; ++d; }
  *dd = d; *ff = d + (s - b);
}

__device__ __noinline__ double survivor_contrib(
    int m, const float* __restrict__ gamma, const float* __restrict__ means,
    const float* __restrict__ weights, const float* __restrict__ xrow) {
  const float* mu = means + m * DDIM;
  float v[DDIM];
#pragma unroll
  for (int d = 0; d < DDIM; ++d) v[d] = xrow[d] - mu[d];
  const float* g = gamma + (size_t)m * DDIM * DDIM;
  float Dex = 0.f;
  for (int e = 0; e < DDIM; ++e) {
    float y = 0.f;
#pragma unroll
    for (int d = 0; d < DDIM; ++d) y += g[d * DDIM + e] * v[d];
    Dex += y * y;
  }
  float e2 = -Dex * 1.44269504088896340736f;
  float kf = floorf(e2);
  float mant = exp2f(e2 - kf);
  return ldexp((double)(weights[m] * mant), (int)kf);
}

// ---------------------------------------------------------------------------
// The fused cooperative kernel.
// ---------------------------------------------------------------------------
__global__ __launch_bounds__(TPB, 1) void fused_kernel(
    const float* __restrict__ x, const float* __restrict__ gamma,
    const float* __restrict__ means, const float* __restrict__ weights,
    unsigned short* __restrict__ Bm, unsigned int* __restrict__ mcnt,
    unsigned short* __restrict__ mlist, unsigned int* __restrict__ flist,
    unsigned int* __restrict__ fcount, double* __restrict__ acc_g,
    float* __restrict__ out) {
  extern __shared__ __align__(16) unsigned short As[];   // ROWS * KSYM bf16
  cg::grid_group grid = cg::this_grid();
  const int t = threadIdx.x;
  const int blk = blockIdx.x;

  // ================= Phase 0: zero acc / mcnt / fcount =================
  {
    if (t < 128) acc_g[blk * 128 + t] = 0.0;
    if (t >= 128 && t < 136) mcnt[blk * 8 + (t - 128)] = 0u;
    if (blk == 0 && t == 136) *fcount = 0u;
  }

  // ================= Phase 1: build bf16 B (8 m per block) =================
  {
    float* G  = (float*)As;                 // [32][33]
    float* C  = G + 32 * 33;                // [32][33]
    float* bv = C + 32 * 33;                // [32]
    float* cp = bv + 32;                    // [1]
#pragma unroll 1
    for (int mi = 0; mi < 8; ++mi) {
      const int m = blk * 8 + mi;
      const float* g = gamma + (size_t)m * DDIM * DDIM;
      const float* mu = means + m * DDIM;
      for (int l = t; l < DDIM * DDIM; l += TPB) G[(l >> 5) * 33 + (l & 31)] = g[l];
      __syncthreads();
      for (int l = t; l < DDIM * DDIM; l += TPB) {
        int d = l >> 5, f = l & 31;
        float c = 0.f;
#pragma unroll
        for (int e = 0; e < DDIM; ++e) c += G[d * 33 + e] * G[f * 33 + e];
        C[d * 33 + f] = c;
      }
      __syncthreads();
      if (t < DDIM) {
        float b = 0.f;
#pragma unroll
        for (int f = 0; f < DDIM; ++f) b += C[t * 33 + f] * mu[f];
        bv[t] = b;
      }
      __syncthreads();
      if (t == 0) {
        float c = 0.f;
#pragma unroll
        for (int d = 0; d < DDIM; ++d) c += bv[d] * mu[d];
        *cp = c;
      }
      __syncthreads();
      unsigned short* brow = Bm + (size_t)m * KSYM;
      const float cc = *cp;
      for (int s = t; s < KSYM; s += TPB) {
        float val;
        if (s < 528) {
          int d, f; slot_df(s, &d, &f);
          val = (d == f) ? C[d * 33 + d] : 2.f * C[d * 33 + f];
        } else if (s < 560) {
          val = -2.f * bv[s - 528];
        } else if (s == 560) {
          val = cc;
        } else if (s == 561) {
          unsigned int hi = to_bf16(cc);
          union { unsigned int u; float f; } xh; xh.u = hi << 16;
          val = cc - xh.f;
        } else {
          val = 0.f;
        }
        brow[s] = (unsigned short)to_bf16(val);
      }
      __syncthreads();
    }
  }

  grid.sync();   // B complete + counters zeroed, visible device-wide

  // ================= Phase 2: bf16 MFMA screen (r12 body) =================
  {
    const int i0 = blk * ROWS;
    const int lane = t & 63, w = t >> 6;
    const int lrow = lane & 15, quad = lane >> 4;
    const int rot = blk & 31;

    // generate A tile into swizzled LDS: row r (128), chunk-quarter j (4)
    {
      const int r = t >> 2, j = t & 3;
      float v[DDIM];
#pragma unroll
      for (int q = 0; q < 8; ++q)
        *(floatx4*)&v[q * 4] = *(const floatx4*)(x + (size_t)(i0 + r) * DDIM + q * 4);
#pragma unroll
      for (int jj = 0; jj < 4; ++jj) {
        if (j == jj) {
#pragma unroll
          for (int cc2 = 0; cc2 < 18; ++cc2) {
            const int c = jj * 18 + cc2;
            unsigned int uu[4];
#pragma unroll
            for (int q = 0; q < 4; ++q) {
              const int s0 = c * 8 + q * 2;
              uu[q] = to_bf16(slot_val(v, s0)) | (to_bf16(slot_val(v, s0 + 1)) << 16);
            }
            const int cs = (c & ~7) | ((c & 7) ^ (r & 7));
            uint4 o; o.x = uu[0]; o.y = uu[1]; o.z = uu[2]; o.w = uu[3];
            *(uint4*)&As[r * KSYM + cs * 8] = o;
          }
        }
      }
    }
    __syncthreads();

#pragma unroll 1
    for (int g = 0; g < 4; ++g) {
      const int mq = ((g * 8 + w) + rot) & 31;
      const int m0 = mq * 64;
      const unsigned short* bb0 = Bm + (size_t)(m0 +  0 + lrow) * KSYM + quad * 8;
      const unsigned short* bb1 = Bm + (size_t)(m0 + 16 + lrow) * KSYM + quad * 8;
      const unsigned short* bb2 = Bm + (size_t)(m0 + 32 + lrow) * KSYM + quad * 8;
      const unsigned short* bb3 = Bm + (size_t)(m0 + 48 + lrow) * KSYM + quad * 8;

      floatx4 acc[8][4] = {};
#pragma unroll
      for (int kk = 0; kk < KSTEPS; ++kk) {
        short8 bf[4];
        bf[0] = *(const short8*)(bb0 + kk * 32);
        bf[1] = *(const short8*)(bb1 + kk * 32);
        bf[2] = *(const short8*)(bb2 + kk * 32);
        bf[3] = *(const short8*)(bb3 + kk * 32);
        short8 af[8];
#pragma unroll
        for (int ti = 0; ti < 8; ++ti) {
          int rr = ti * 16 + lrow;
          int c = kk * 4 + quad;
          int cs = (c & ~7) | ((c & 7) ^ (rr & 7));
          af[ti] = *(const short8*)&As[rr * KSYM + cs * 8];
        }
#pragma unroll
        for (int ti = 0; ti < 8; ++ti)
#pragma unroll
          for (int mj = 0; mj < 4; ++mj)
            acc[ti][mj] = __builtin_amdgcn_mfma_f32_16x16x32_bf16(
                af[ti], bf[mj], acc[ti][mj], 0, 0, 0);
      }

#pragma unroll
      for (int ti = 0; ti < 8; ++ti)
#pragma unroll
        for (int mj = 0; mj < 4; ++mj)
#pragma unroll
          for (int r = 0; r < 4; ++r) {
            float Dt = acc[ti][mj][r];
            if (Dt < SCREEN) {
              int gi = i0 + ti * 16 + quad * 4 + r;
              int gm = m0 + mj * 16 + lrow;
              unsigned int idx = atomicAdd(&mcnt[gm], 1u);
              if (idx < MCAP) {
                mlist[(size_t)gm * MCAP + idx] = (unsigned short)gi;
              } else {
                unsigned int fi = atomicAdd(fcount, 1u);
                if (fi < FCAP)
                  flist[fi] = ((unsigned int)gi << 11) | (unsigned int)gm;
              }
            }
          }
    }
  }

  grid.sync();   // survivor lists complete

  // ================= Phase 3: survivor processing =================
  {
    float* Gt = (float*)As;                 // [32][33]: Gt[e][d] = G[d][e]
    float* mus = Gt + 32 * 33;              // [32]
#pragma unroll 1
    for (int mi = 0; mi < 8; ++mi) {
      const int m = blk * 8 + mi;
      unsigned int cnt = mcnt[m];
      if (cnt > MCAP) cnt = MCAP;
      if (cnt > 0) {                         // block-uniform condition
        const float* g = gamma + (size_t)m * DDIM * DDIM;
        for (int l = t; l < DDIM * DDIM; l += TPB) Gt[(l & 31) * 33 + (l >> 5)] = g[l];
        if (t < DDIM) mus[t] = means[m * DDIM + t];
        __syncthreads();
        const float wm = weights[m];
        for (unsigned int s = t; s < cnt; s += TPB) {
          int gi = mlist[(size_t)m * MCAP + s];
          float v[DDIM];
#pragma unroll
          for (int q = 0; q < 8; ++q) {
            floatx4 xv = *(const floatx4*)(x + (size_t)gi * DDIM + q * 4);
            v[q * 4 + 0] = xv.x - mus[q * 4 + 0];
            v[q * 4 + 1] = xv.y - mus[q * 4 + 1];
            v[q * 4 + 2] = xv.z - mus[q * 4 + 2];
            v[q * 4 + 3] = xv.w - mus[q * 4 + 3];
          }
          float Dex = 0.f;
#pragma unroll
          for (int e = 0; e < DDIM; ++e) {
            float y = 0.f;
#pragma unroll
            for (int d = 0; d < DDIM; ++d) y += Gt[e * 33 + d] * v[d];
            Dex += y * y;
          }
          float e2 = -Dex * 1.44269504088896340736f;
          float kf = floorf(e2);
          float mant = exp2f(e2 - kf);
          atomicAdd(&acc_g[gi], ldexp((double)(wm * mant), (int)kf));
        }
        __syncthreads();
      }
    }
    // fallback flat list, grid-strided
    unsigned int total = *fcount;
    if (total > FCAP) total = FCAP;
    for (unsigned int idx = blk * TPB + t; idx < total; idx += GRID * TPB) {
      unsigned int pck = flist[idx];
      int gi = (int)(pck >> 11), gm = (int)(pck & 2047u);
      double c = survivor_contrib(gm, gamma, means, weights, x + (size_t)gi * DDIM);
      atomicAdd(&acc_g[gi], c);
    }
  }

  grid.sync();   // acc final

  // ================= Phase 4: finalize =================
  if (t < 128) {
    int i = blk * 128 + t;
    out[i] = (float)acc_g[i];
  }
}

extern "C" void kernel_launch(void* const* d_in, const int* in_sizes, int n_in,
                              void* d_out, int out_size, void* d_ws, size_t ws_size,
                              hipStream_t stream) {
  (void)in_sizes; (void)n_in; (void)out_size;
  const float* x       = (const float*)d_in[0];   // [N][32]
  const float* gamma   = (const float*)d_in[1];   // [M][32][32]
  const float* means   = (const float*)d_in[2];   // [M][32]
  const float* weights = (const float*)d_in[3];   // [M]
  float* outp          = (float*)d_out;

  char* p = (char*)d_ws;
  double* acc          = (double*)p;            p += (size_t)NN * 8;
  unsigned int* fcount = (unsigned int*)p;      p += 16;
  unsigned int* mcnt   = (unsigned int*)p;      p += (size_t)MM * 4;
  unsigned short* mlist= (unsigned short*)p;    p += (size_t)MM * MCAP * 2;
  unsigned int* flist  = (unsigned int*)p;      p += (size_t)FCAP * 4;
  unsigned short* Bm   = (unsigned short*)p;    p += (size_t)MM * KSYM * 2;
  const size_t needed = (size_t)(p - (char*)d_ws);
  if (ws_size < needed) return;

  (void)hipFuncSetAttribute((const void*)fused_kernel,
                            hipFuncAttributeMaxDynamicSharedMemorySize,
                            ROWS * KSYM * 2);

  void* args[] = {(void*)&x, (void*)&gamma, (void*)&means, (void*)&weights,
                  (void*)&Bm, (void*)&mcnt, (void*)&mlist, (void*)&flist,
                  (void*)&fcount, (void*)&acc, (void*)&outp};
  hipLaunchCooperativeKernel((const void*)fused_kernel, dim3(GRID), dim3(TPB),
                             args, ROWS * KSYM * 2, stream);
}

// Round 14
// 194.410 us; speedup vs baseline: 1.7939x; 1.7939x over previous
//
#include <hip/hip_runtime.h>
#include <math.h>

// RBF mixture: out[i] = sum_m w_m * exp(-(x_i-mu_m)^T C_m (x_i-mu_m)), C_m = G_m G_m^T
// N=32768, M=2048, D=32.
// Round 14: screen at 1 wave/SIMD with the FULL 512-reg budget.
// TPB=256 (4 waves), ROWS=128, 147 KB LDS A-tile -> 1 block/CU, 1 wave/SIMD,
// launch_bounds(256,1): acc[8][4] + 6-deep B register ring + af with zero
// spill (every 2-waves/SIMD config was capped at 256 regs -> compiler
// couldn't hold lookahead: r6 sunk prefetches, r9 ring neutral, r10/r12
// spilled 9.7 MB). ILP replaces TLP: 32-MFMA bursts hide LDS/L2 latency
// behind a ring that runs 6 ksteps ahead. build_b now zeros acc/mcnt/fcount
// (memset dispatch dropped). Survivor path unchanged from r12.

#define NN 32768
#define MM 2048
#define DDIM 32
#define KSYM 576           // 528 triangle + 32 cross + 2 const + 14 pad = 18*32
#define ROWS 128           // i-rows per screen block
#define KSTEPS 18
#define PIPE 6             // B-ring depth
#define SCREEN 120.0f
#define MCAP 2048
#define FCAP 1000000
#define FBLK 64

typedef __attribute__((ext_vector_type(8))) short short8;
typedef __attribute__((ext_vector_type(4))) float floatx4;

__device__ __forceinline__ unsigned int to_bf16(float f) {
  union { float f; unsigned int u; } x; x.f = f;
  return (x.u + 0x7fffu + ((x.u >> 16) & 1u)) >> 16;   // RNE, finite inputs only
}

struct DFTab { unsigned char d[528]; unsigned char f[528]; };
constexpr DFTab make_df() {
  DFTab t{};
  int s = 0;
  for (int d = 0; d < 32; ++d)
    for (int f = d; f < 32; ++f) {
      t.d[s] = (unsigned char)d; t.f[s] = (unsigned char)f; ++s;
    }
  return t;
}
constexpr DFTab DFT = make_df();

__device__ __forceinline__ float slot_val(const float* v, int s) {
  if (s < 528) return v[DFT.d[s]] * v[DFT.f[s]];
  if (s < 560) return v[s - 528];
  if (s < 562) return 1.f;
  return 0.f;
}

__device__ __forceinline__ void slot_df(int s, int* dd, int* ff) {
  int d = 0, b = 0;
  while (b + (DDIM - d) <= s) { b += DDIM - d; ++d; }
  *dd = d; *ff = d + (s - b);
}

// ---------------------------------------------------------------------------
// Kernel 1: bf16 B-matrix [M][KSYM] + zero acc/mcnt/fcount (fused memset).
// ---------------------------------------------------------------------------
__global__ __launch_bounds__(256) void build_b_kernel(
    const float* __restrict__ gamma, const float* __restrict__ means,
    unsigned short* __restrict__ Bm, double* __restrict__ acc,
    unsigned int* __restrict__ mcnt, unsigned int* __restrict__ fcount) {
  __shared__ float G[DDIM][DDIM + 1];
  __shared__ float C[DDIM][DDIM + 1];
  __shared__ float bv[DDIM];
  __shared__ float cc;
  const int m = blockIdx.x;
  const int t = threadIdx.x;
  // fused zeroing: 2048 blocks x 16 doubles = 32768 acc entries
  if (t < 16) acc[m * 16 + t] = 0.0;
  if (t == 16) mcnt[m] = 0u;
  if (m == 0 && t == 17) *fcount = 0u;
  const float* g = gamma + (size_t)m * DDIM * DDIM;
  for (int l = t; l < DDIM * DDIM; l += 256) G[l >> 5][l & 31] = g[l];
  __syncthreads();
  const float* mu = means + m * DDIM;
  for (int l = t; l < DDIM * DDIM; l += 256) {
    int d = l >> 5, f = l & 31;
    float c = 0.f;
#pragma unroll
    for (int e = 0; e < DDIM; ++e) c += G[d][e] * G[f][e];
    C[d][f] = c;
  }
  __syncthreads();
  if (t < DDIM) {
    float b = 0.f;
#pragma unroll
    for (int f = 0; f < DDIM; ++f) b += C[t][f] * mu[f];
    bv[t] = b;
  }
  __syncthreads();
  if (t == 0) {
    float c = 0.f;
#pragma unroll
    for (int d = 0; d < DDIM; ++d) c += bv[d] * mu[d];
    cc = c;
  }
  __syncthreads();
  unsigned short* brow = Bm + (size_t)m * KSYM;
  for (int s = t; s < KSYM; s += 256) {
    float val;
    if (s < 528) {
      int d, f; slot_df(s, &d, &f);
      val = (d == f) ? C[d][d] : 2.f * C[d][f];
    } else if (s < 560) {
      val = -2.f * bv[s - 528];
    } else if (s == 560) {
      val = cc;
    } else if (s == 561) {
      unsigned int hi = to_bf16(cc);
      union { unsigned int u; float f; } xh; xh.u = hi << 16;
      val = cc - xh.f;
    } else {
      val = 0.f;
    }
    brow[s] = (unsigned short)to_bf16(val);
  }
}

// ---------------------------------------------------------------------------
// Exact scalar path (fallback list only).
// ---------------------------------------------------------------------------
__device__ __noinline__ double survivor_contrib(
    int m, const float* __restrict__ gamma, const float* __restrict__ means,
    const float* __restrict__ weights, const float* __restrict__ xrow) {
  const float* mu = means + m * DDIM;
  float v[DDIM];
#pragma unroll
  for (int d = 0; d < DDIM; ++d) v[d] = xrow[d] - mu[d];
  const float* g = gamma + (size_t)m * DDIM * DDIM;
  float Dex = 0.f;
  for (int e = 0; e < DDIM; ++e) {
    float y = 0.f;
#pragma unroll
    for (int d = 0; d < DDIM; ++d) y += g[d * DDIM + e] * v[d];
    Dex += y * y;
  }
  float e2 = -Dex * 1.44269504088896340736f;
  float kf = floorf(e2);
  float mant = exp2f(e2 - kf);
  return ldexp((double)(weights[m] * mant), (int)kf);
}

// ---------------------------------------------------------------------------
// Kernel 2: bf16 MFMA screen, 1 wave/SIMD + full register file.
// 256 thr (4 waves), 128-row A-tile in 147 KB dynamic LDS (XOR swizzle,
// 0 conflicts r3-r12), 1 block/CU. launch_bounds(256,1) -> 512 regs/wave:
// acc[8][4] (128 AGPR) + ring[6][4] (96) + af (32 transient) + addr, no
// spill, loads 6 ksteps ahead. Wave w sweeps m-quads ((g*4+w)+rot)&31,
// g=0..7. Per kstep: 4 B-loads + 8 ds_read_b128 + 32 MFMA (1088-cyc burst).
// Frag layout (m89/m97): A/B [row=lane&15][k=quad*8+j]; C/D col=lane&15,
// row=quad*4+reg. Survivors -> per-m bucket lists; overflow -> flat list.
// ---------------------------------------------------------------------------
__global__ __launch_bounds__(256, 1) void screen_kernel(
    const float* __restrict__ x, const unsigned short* __restrict__ Bm,
    unsigned int* __restrict__ mcnt, unsigned short* __restrict__ mlist,
    unsigned int* __restrict__ flist, unsigned int* __restrict__ fcount) {
  extern __shared__ __align__(16) unsigned short As[];   // ROWS * KSYM
  const int t = threadIdx.x;
  const int i0 = blockIdx.x * ROWS;
  const int lane = t & 63, w = t >> 6;                   // w in [0,4)
  const int lrow = lane & 15, quad = lane >> 4;
  const int rot = blockIdx.x & 31;

  // ---- generate A tile into swizzled LDS: row r (128), half j (2 x 36 chunks) ----
  {
    const int r = t >> 1, j = t & 1;
    float v[DDIM];
#pragma unroll
    for (int q = 0; q < 8; ++q)
      *(floatx4*)&v[q * 4] = *(const floatx4*)(x + (size_t)(i0 + r) * DDIM + q * 4);
#pragma unroll
    for (int jj = 0; jj < 2; ++jj) {
      if (j == jj) {
#pragma unroll
        for (int cc2 = 0; cc2 < 36; ++cc2) {
          const int c = jj * 36 + cc2;                   // 16B chunk index 0..71
          unsigned int uu[4];
#pragma unroll
          for (int q = 0; q < 4; ++q) {
            const int s0 = c * 8 + q * 2;
            uu[q] = to_bf16(slot_val(v, s0)) | (to_bf16(slot_val(v, s0 + 1)) << 16);
          }
          const int cs = (c & ~7) | ((c & 7) ^ (r & 7));
          uint4 o; o.x = uu[0]; o.y = uu[1]; o.z = uu[2]; o.w = uu[3];
          *(uint4*)&As[r * KSYM + cs * 8] = o;
        }
      }
    }
  }
  __syncthreads();

#pragma unroll 1
  for (int g = 0; g < 8; ++g) {
    const int mq = ((g * 4 + w) + rot) & 31;
    const int m0 = mq * 64;
    const unsigned short* bb0 = Bm + (size_t)(m0 +  0 + lrow) * KSYM + quad * 8;
    const unsigned short* bb1 = Bm + (size_t)(m0 + 16 + lrow) * KSYM + quad * 8;
    const unsigned short* bb2 = Bm + (size_t)(m0 + 32 + lrow) * KSYM + quad * 8;
    const unsigned short* bb3 = Bm + (size_t)(m0 + 48 + lrow) * KSYM + quad * 8;

    floatx4 acc[8][4] = {};                              // [ti][mj]
    short8 ring[PIPE][4];

    // prologue: ksteps 0..5 in flight
#pragma unroll
    for (int p = 0; p < PIPE; ++p) {
      ring[p][0] = *(const short8*)(bb0 + p * 32);
      ring[p][1] = *(const short8*)(bb1 + p * 32);
      ring[p][2] = *(const short8*)(bb2 + p * 32);
      ring[p][3] = *(const short8*)(bb3 + p * 32);
    }

    // steady: 2 groups of 6; compute kstep kb*6+u from slot u, refill with +6
#pragma unroll 1
    for (int kb = 0; kb < 2; ++kb) {
#pragma unroll
      for (int u = 0; u < PIPE; ++u) {
        const int kk = kb * PIPE + u;
        short8 af[8];
#pragma unroll
        for (int ti = 0; ti < 8; ++ti) {
          int rr = ti * 16 + lrow;
          int c = kk * 4 + quad;
          int cs = (c & ~7) | ((c & 7) ^ (rr & 7));
          af[ti] = *(const short8*)&As[rr * KSYM + cs * 8];
        }
#pragma unroll
        for (int ti = 0; ti < 8; ++ti)
#pragma unroll
          for (int mj = 0; mj < 4; ++mj)
            acc[ti][mj] = __builtin_amdgcn_mfma_f32_16x16x32_bf16(
                af[ti], ring[u][mj], acc[ti][mj], 0, 0, 0);
        const int kn = kk + PIPE;
        ring[u][0] = *(const short8*)(bb0 + kn * 32);
        ring[u][1] = *(const short8*)(bb1 + kn * 32);
        ring[u][2] = *(const short8*)(bb2 + kn * 32);
        ring[u][3] = *(const short8*)(bb3 + kn * 32);
      }
    }

    // drain: ksteps 12..17 from slots 0..5
#pragma unroll
    for (int u = 0; u < PIPE; ++u) {
      const int kk = 2 * PIPE + u;
      short8 af[8];
#pragma unroll
      for (int ti = 0; ti < 8; ++ti) {
        int rr = ti * 16 + lrow;
        int c = kk * 4 + quad;
        int cs = (c & ~7) | ((c & 7) ^ (rr & 7));
        af[ti] = *(const short8*)&As[rr * KSYM + cs * 8];
      }
#pragma unroll
      for (int ti = 0; ti < 8; ++ti)
#pragma unroll
        for (int mj = 0; mj < 4; ++mj)
          acc[ti][mj] = __builtin_amdgcn_mfma_f32_16x16x32_bf16(
              af[ti], ring[u][mj], acc[ti][mj], 0, 0, 0);
    }

    // screen & emit survivors (rare) into per-m buckets
#pragma unroll
    for (int ti = 0; ti < 8; ++ti)
#pragma unroll
      for (int mj = 0; mj < 4; ++mj)
#pragma unroll
        for (int r = 0; r < 4; ++r) {
          float Dt = acc[ti][mj][r];
          if (Dt < SCREEN) {
            int gi = i0 + ti * 16 + quad * 4 + r;
            int gm = m0 + mj * 16 + lrow;
            unsigned int idx = atomicAdd(&mcnt[gm], 1u);
            if (idx < MCAP) {
              mlist[(size_t)gm * MCAP + idx] = (unsigned short)gi;
            } else {
              unsigned int fi = atomicAdd(fcount, 1u);
              if (fi < FCAP)
                flist[fi] = ((unsigned int)gi << 11) | (unsigned int)gm;
            }
          }
        }
  }
}

// ---------------------------------------------------------------------------
// Kernel 3: survivor processing (per-m buckets + fallback list).
// ---------------------------------------------------------------------------
__global__ __launch_bounds__(256) void survivor2_kernel(
    const unsigned int* __restrict__ mcnt, const unsigned short* __restrict__ mlist,
    const unsigned int* __restrict__ flist, const unsigned int* __restrict__ fcount,
    const float* __restrict__ x, const float* __restrict__ gamma,
    const float* __restrict__ means, const float* __restrict__ weights,
    double* __restrict__ acc_out) {
  const int blk = blockIdx.x;
  const int t = threadIdx.x;
  if (blk >= MM) {                                       // fallback path
    unsigned int total = *fcount;
    if (total > FCAP) total = FCAP;
    for (unsigned int idx = (blk - MM) * 256 + t; idx < total; idx += FBLK * 256) {
      unsigned int p = flist[idx];
      int gi = (int)(p >> 11), gm = (int)(p & 2047u);
      double c = survivor_contrib(gm, gamma, means, weights, x + (size_t)gi * DDIM);
      atomicAdd(&acc_out[gi], c);
    }
    return;
  }
  __shared__ float Gt[DDIM][DDIM + 1];
  __shared__ float mu[DDIM];
  const int m = blk;
  unsigned int cnt = mcnt[m];
  if (cnt > MCAP) cnt = MCAP;
  if (cnt == 0) return;
  const float* g = gamma + (size_t)m * DDIM * DDIM;
  for (int l = t; l < DDIM * DDIM; l += 256) Gt[l & 31][l >> 5] = g[l];
  if (t < DDIM) mu[t] = means[m * DDIM + t];
  __syncthreads();
  const float wm = weights[m];
  for (unsigned int s = t; s < cnt; s += 256) {
    int gi = mlist[(size_t)m * MCAP + s];
    float v[DDIM];
#pragma unroll
    for (int q = 0; q < 8; ++q) {
      floatx4 xv = *(const floatx4*)(x + (size_t)gi * DDIM + q * 4);
      v[q * 4 + 0] = xv.x - mu[q * 4 + 0];
      v[q * 4 + 1] = xv.y - mu[q * 4 + 1];
      v[q * 4 + 2] = xv.z - mu[q * 4 + 2];
      v[q * 4 + 3] = xv.w - mu[q * 4 + 3];
    }
    float Dex = 0.f;
#pragma unroll
    for (int e = 0; e < DDIM; ++e) {
      float y = 0.f;
#pragma unroll
      for (int d = 0; d < DDIM; ++d) y += Gt[e][d] * v[d];
      Dex += y * y;
    }
    float e2 = -Dex * 1.44269504088896340736f;
    float kf = floorf(e2);
    float mant = exp2f(e2 - kf);
    atomicAdd(&acc_out[gi], ldexp((double)(wm * mant), (int)kf));
  }
}

__global__ __launch_bounds__(256) void finalize_kernel(
    const double* __restrict__ acc, float* __restrict__ out) {
  int i = blockIdx.x * 256 + threadIdx.x;
  out[i] = (float)acc[i];
}

extern "C" void kernel_launch(void* const* d_in, const int* in_sizes, int n_in,
                              void* d_out, int out_size, void* d_ws, size_t ws_size,
                              hipStream_t stream) {
  (void)in_sizes; (void)n_in; (void)out_size;
  const float* x       = (const float*)d_in[0];   // [N][32]
  const float* gamma   = (const float*)d_in[1];   // [M][32][32]
  const float* means   = (const float*)d_in[2];   // [M][32]
  const float* weights = (const float*)d_in[3];   // [M]

  char* p = (char*)d_ws;
  double* acc          = (double*)p;            p += (size_t)NN * 8;
  unsigned int* fcount = (unsigned int*)p;      p += 16;
  unsigned int* mcnt   = (unsigned int*)p;      p += (size_t)MM * 4;
  unsigned short* mlist= (unsigned short*)p;    p += (size_t)MM * MCAP * 2;
  unsigned int* flist  = (unsigned int*)p;      p += (size_t)FCAP * 4;
  unsigned short* Bm   = (unsigned short*)p;    p += (size_t)MM * KSYM * 2;
  const size_t needed = (size_t)(p - (char*)d_ws);
  if (ws_size < needed) return;

  (void)hipFuncSetAttribute((const void*)screen_kernel,
                            hipFuncAttributeMaxDynamicSharedMemorySize,
                            ROWS * KSYM * 2);

  hipLaunchKernelGGL(build_b_kernel, dim3(MM), dim3(256), 0, stream,
                     gamma, means, Bm, acc, mcnt, fcount);
  hipLaunchKernelGGL(screen_kernel, dim3(NN / ROWS), dim3(256),
                     ROWS * KSYM * 2, stream,
                     x, Bm, mcnt, mlist, flist, fcount);
  hipLaunchKernelGGL(survivor2_kernel, dim3(MM + FBLK), dim3(256), 0, stream,
                     mcnt, mlist, flist, fcount, x, gamma, means, weights, acc);
  hipLaunchKernelGGL(finalize_kernel, dim3(NN / 256), dim3(256), 0, stream,
                     acc, (float*)d_out);
}